// Round 2
// baseline (88.948 us; speedup 1.0000x reference)
//
#include <hip/hip_runtime.h>
#include <math.h>

// KAN layer: B=8192, IN_F=OUT_F=1024, GRID=5. idx_in == identity => x = X.
// Spline via exact ramp-sum (G=5, integer breakpoints in t-space):
//   s(t) = c0 + sum_i (c[i+1]-c[i]) * clamp(t-i, 0, 1),  t = 2*clamp(x,-1,1)+2
// Pure VALU (med3+fma), no dynamic indexing, no LDS.
//
// R2 changes vs R1: 1024 blocks x 8 rows (preamble amortized 2x, 8 float4
// loads in flight per thread); param preamble as aligned float4 loads
// (thread t owns 4 consecutive cols -> coeffs is 20 contiguous floats at
// t*80B, W is 8 floats at t*32B, bias 4 floats at t*16B).

#define B_ROWS   8192
#define N_FEAT   1024
#define N_BLOCKS 1024
#define ROWS_PER_BLOCK (B_ROWS / N_BLOCKS)   // 8

__global__ __launch_bounds__(256) void kan_kernel(
    const float* __restrict__ X,
    const float* __restrict__ coeffs,   // (1024, 5) row-major
    const float* __restrict__ W,        // (1024, 2) row-major
    const float* __restrict__ bias,     // (1024,)
    float* __restrict__ Y)
{
    const int t    = threadIdx.x;   // 0..255
    const int col0 = t * 4;         // columns col0..col0+3

    // ---- vectorized per-column param preamble (8 float4 loads) ----
    float craw[20];                  // coeffs for 4 consecutive cols
    {
        const float4* cg = reinterpret_cast<const float4*>(coeffs + (size_t)col0 * 5);
        float4* cr = reinterpret_cast<float4*>(craw);
#pragma unroll
        for (int q = 0; q < 5; ++q) cr[q] = cg[q];
    }
    float wraw[8];
    {
        const float4* wg = reinterpret_cast<const float4*>(W + (size_t)col0 * 2);
        float4* wr = reinterpret_cast<float4*>(wraw);
        wr[0] = wg[0]; wr[1] = wg[1];
    }
    const float4 b4 = *reinterpret_cast<const float4*>(bias + col0);
    const float bb[4] = {b4.x, b4.y, b4.z, b4.w};

    float c0[4], d0[4], d1[4], d2[4], d3[4], w0[4], w1[4];
#pragma unroll
    for (int j = 0; j < 4; ++j) {
        const float a0 = craw[j * 5 + 0], a1 = craw[j * 5 + 1], a2 = craw[j * 5 + 2];
        const float a3 = craw[j * 5 + 3], a4 = craw[j * 5 + 4];
        c0[j] = a0;
        d0[j] = a1 - a0;
        d1[j] = a2 - a1;
        d2[j] = a3 - a2;
        d3[j] = a4 - a3;
        w0[j] = wraw[j * 2 + 0];
        w1[j] = wraw[j * 2 + 1];
    }

    // ---- issue all 8 row loads up front (8 KB of X in flight/thread) ----
    float4 x4[ROWS_PER_BLOCK];
#pragma unroll
    for (int i = 0; i < ROWS_PER_BLOCK; ++i) {
        const int row = blockIdx.x + i * N_BLOCKS;
        x4[i] = *reinterpret_cast<const float4*>(X + (size_t)row * N_FEAT + col0);
    }

#pragma unroll
    for (int i = 0; i < ROWS_PER_BLOCK; ++i) {
        const int row = blockIdx.x + i * N_BLOCKS;
        const float xs[4] = {x4[i].x, x4[i].y, x4[i].z, x4[i].w};
        float ys[4];

#pragma unroll
        for (int j = 0; j < 4; ++j) {
            const float x = xs[j];

            // silu(x) = x / (1 + exp(-x))
            const float sig  = 1.0f / (1.0f + __expf(-x));
            const float silu = x * sig;

            // ramp-sum spline
            const float xc = fminf(fmaxf(x, -1.0f), 1.0f);   // -> v_med3
            const float tt = fmaf(2.0f, xc, 2.0f);           // [0,4]
            const float r0 = fminf(tt, 1.0f);
            const float r1 = fminf(fmaxf(tt - 1.0f, 0.0f), 1.0f);
            const float r2 = fminf(fmaxf(tt - 2.0f, 0.0f), 1.0f);
            const float r3 = fminf(fmaxf(tt - 3.0f, 0.0f), 1.0f);
            float s = fmaf(d0[j], r0, c0[j]);
            s = fmaf(d1[j], r1, s);
            s = fmaf(d2[j], r2, s);
            s = fmaf(d3[j], r3, s);

            ys[j] = fmaf(silu, w0[j], fmaf(s, w1[j], bb[j]));
        }

        *reinterpret_cast<float4*>(Y + (size_t)row * N_FEAT + col0) =
            make_float4(ys[0], ys[1], ys[2], ys[3]);
    }
}

extern "C" void kernel_launch(void* const* d_in, const int* in_sizes, int n_in,
                              void* d_out, int out_size, void* d_ws, size_t ws_size,
                              hipStream_t stream) {
    const float* X      = (const float*)d_in[0];   // (8192, 1024)
    const float* coeffs = (const float*)d_in[1];   // (1024, 5)
    const float* W      = (const float*)d_in[2];   // (1024, 2)
    const float* b      = (const float*)d_in[3];   // (1024,)
    float* Y            = (float*)d_out;           // (8192, 1024)

    kan_kernel<<<N_BLOCKS, 256, 0, stream>>>(X, coeffs, W, b, Y);
}